// Round 1
// baseline (6128.167 us; speedup 1.0000x reference)
//
#include <hip/hip_runtime.h>
#include <hip/hip_bf16.h>
#include <math.h>

namespace {

constexpr int T = 1024;      // sequence length
constexpr int D = 768;       // model dim
constexpr int FF = 3072;     // ffn dim
constexpr int H = 12;        // heads
constexpr int HD = 64;       // head dim
constexpr int L = 12;        // layers
constexpr float NEG = -3.4028234663852886e38f;  // finfo(f32).min
constexpr float SCALE = 0.125f;                 // 1/sqrt(64)

// ---------------- embedding: h0 = wte[ids] + wpe ----------------
__global__ void embed_kernel(const int* __restrict__ ids,
                             const float* __restrict__ wte,
                             const float* __restrict__ wpe,
                             float* __restrict__ h) {
    int i = blockIdx.x * blockDim.x + threadIdx.x;
    if (i >= T * D) return;
    int t = i / D, d = i % D;
    h[i] = wte[(long)ids[t] * D + d] + wpe[i];
}

// ---------------- layernorm over D=768, one row per block (256 thr) ----------------
__global__ __launch_bounds__(256)
void ln_kernel(const float* __restrict__ x, const float* __restrict__ g,
               const float* __restrict__ b, float* __restrict__ out) {
    int row = blockIdx.x, tid = threadIdx.x;
    const float* xr = x + (long)row * D;
    float v0 = xr[tid], v1 = xr[tid + 256], v2 = xr[tid + 512];
    __shared__ float red[4];
    __shared__ float share;
    float s = v0 + v1 + v2;
#pragma unroll
    for (int o = 32; o; o >>= 1) s += __shfl_down(s, o, 64);
    if ((tid & 63) == 0) red[tid >> 6] = s;
    __syncthreads();
    if (tid == 0) share = (red[0] + red[1] + red[2] + red[3]) * (1.0f / D);
    __syncthreads();
    float mu = share;
    float d0 = v0 - mu, d1 = v1 - mu, d2 = v2 - mu;
    float q = d0 * d0 + d1 * d1 + d2 * d2;
#pragma unroll
    for (int o = 32; o; o >>= 1) q += __shfl_down(q, o, 64);
    __syncthreads();   // protect red reuse
    if ((tid & 63) == 0) red[tid >> 6] = q;
    __syncthreads();
    if (tid == 0) share = rsqrtf((red[0] + red[1] + red[2] + red[3]) * (1.0f / D) + 1e-5f);
    __syncthreads();
    float rs = share;
    float* orow = out + (long)row * D;
    orow[tid]       = d0 * rs * g[tid]       + b[tid];
    orow[tid + 256] = d1 * rs * g[tid + 256] + b[tid + 256];
    orow[tid + 512] = d2 * rs * g[tid + 512] + b[tid + 512];
}

// ---------------- generic fp32 GEMM C = A@B (+bias)(+gelu)(+resid) ----------------
// 64x64 tile, BK=16, 256 threads, 4x4 micro-tile. All dims assumed %64 / %16.
// flags: 1=bias(per col), 2=resid add (ld==ldc), 4=gelu(tanh)
__global__ __launch_bounds__(256)
void gemm_nn(const float* __restrict__ A, const float* __restrict__ B,
             const float* __restrict__ bias, const float* __restrict__ resid,
             float* __restrict__ C,
             int K, int lda, int ldb, int ldc,
             long batchA, long batchB, long batchC, int flags) {
    A += (long)blockIdx.z * batchA;
    B += (long)blockIdx.z * batchB;
    C += (long)blockIdx.z * batchC;
    __shared__ float As[16][65];
    __shared__ float Bs[16][64];
    const int row0 = blockIdx.y * 64, col0 = blockIdx.x * 64;
    const int tid = threadIdx.x;
    const int tx = tid & 15, ty = tid >> 4;
    const int ar = tid >> 2, ac = (tid & 3) * 4;   // A tile load coords
    const int br = tid >> 4, bc = (tid & 15) * 4;  // B tile load coords
    float acc[4][4] = {};
    for (int k0 = 0; k0 < K; k0 += 16) {
        float4 av = *(const float4*)(A + (long)(row0 + ar) * lda + k0 + ac);
        float4 bv = *(const float4*)(B + (long)(k0 + br) * ldb + col0 + bc);
        As[ac + 0][ar] = av.x; As[ac + 1][ar] = av.y;
        As[ac + 2][ar] = av.z; As[ac + 3][ar] = av.w;
        *(float4*)&Bs[br][bc] = bv;
        __syncthreads();
#pragma unroll
        for (int kk = 0; kk < 16; kk++) {
            float a0 = As[kk][ty * 4 + 0], a1 = As[kk][ty * 4 + 1];
            float a2 = As[kk][ty * 4 + 2], a3 = As[kk][ty * 4 + 3];
            float b0 = Bs[kk][tx * 4 + 0], b1 = Bs[kk][tx * 4 + 1];
            float b2 = Bs[kk][tx * 4 + 2], b3 = Bs[kk][tx * 4 + 3];
            acc[0][0] += a0 * b0; acc[0][1] += a0 * b1; acc[0][2] += a0 * b2; acc[0][3] += a0 * b3;
            acc[1][0] += a1 * b0; acc[1][1] += a1 * b1; acc[1][2] += a1 * b2; acc[1][3] += a1 * b3;
            acc[2][0] += a2 * b0; acc[2][1] += a2 * b1; acc[2][2] += a2 * b2; acc[2][3] += a2 * b3;
            acc[3][0] += a3 * b0; acc[3][1] += a3 * b1; acc[3][2] += a3 * b2; acc[3][3] += a3 * b3;
        }
        __syncthreads();
    }
#pragma unroll
    for (int i = 0; i < 4; i++) {
        int r = row0 + ty * 4 + i;
#pragma unroll
        for (int j = 0; j < 4; j++) {
            int c = col0 + tx * 4 + j;
            float v = acc[i][j];
            if (flags & 1) v += bias[c];
            if (flags & 4) {
                v = 0.5f * v * (1.0f + tanhf(0.7978845608028654f * (v + 0.044715f * v * v * v)));
            }
            if (flags & 2) v += resid[(long)r * ldc + c];
            C[(long)r * ldc + c] = v;
        }
    }
}

// ---------------- NT GEMM for scores: C[i][j] = sum_k A[i,k]*B[j,k], causal block skip ----------------
__global__ __launch_bounds__(256)
void gemm_nt_causal(const float* __restrict__ A, const float* __restrict__ B,
                    float* __restrict__ C,
                    int K, int lda, int ldb, int ldc,
                    long batchA, long batchB, long batchC) {
    const int row0 = blockIdx.y * 64, col0 = blockIdx.x * 64;
    if (col0 > row0 + 63) return;   // entirely above diagonal -> masked out later
    A += (long)blockIdx.z * batchA;
    B += (long)blockIdx.z * batchB;
    C += (long)blockIdx.z * batchC;
    __shared__ float As[16][65];
    __shared__ float Bs[16][65];
    const int tid = threadIdx.x;
    const int tx = tid & 15, ty = tid >> 4;
    const int ar = tid >> 2, ac = (tid & 3) * 4;
    float acc[4][4] = {};
    for (int k0 = 0; k0 < K; k0 += 16) {
        float4 av = *(const float4*)(A + (long)(row0 + ar) * lda + k0 + ac);
        float4 bv = *(const float4*)(B + (long)(col0 + ar) * ldb + k0 + ac);
        As[ac + 0][ar] = av.x; As[ac + 1][ar] = av.y;
        As[ac + 2][ar] = av.z; As[ac + 3][ar] = av.w;
        Bs[ac + 0][ar] = bv.x; Bs[ac + 1][ar] = bv.y;
        Bs[ac + 2][ar] = bv.z; Bs[ac + 3][ar] = bv.w;
        __syncthreads();
#pragma unroll
        for (int kk = 0; kk < 16; kk++) {
            float a0 = As[kk][ty * 4 + 0], a1 = As[kk][ty * 4 + 1];
            float a2 = As[kk][ty * 4 + 2], a3 = As[kk][ty * 4 + 3];
            float b0 = Bs[kk][tx * 4 + 0], b1 = Bs[kk][tx * 4 + 1];
            float b2 = Bs[kk][tx * 4 + 2], b3 = Bs[kk][tx * 4 + 3];
            acc[0][0] += a0 * b0; acc[0][1] += a0 * b1; acc[0][2] += a0 * b2; acc[0][3] += a0 * b3;
            acc[1][0] += a1 * b0; acc[1][1] += a1 * b1; acc[1][2] += a1 * b2; acc[1][3] += a1 * b3;
            acc[2][0] += a2 * b0; acc[2][1] += a2 * b1; acc[2][2] += a2 * b2; acc[2][3] += a2 * b3;
            acc[3][0] += a3 * b0; acc[3][1] += a3 * b1; acc[3][2] += a3 * b2; acc[3][3] += a3 * b3;
        }
        __syncthreads();
    }
#pragma unroll
    for (int i = 0; i < 4; i++) {
        int r = row0 + ty * 4 + i;
#pragma unroll
        for (int j = 0; j < 4; j++) {
            int c = col0 + tx * 4 + j;
            C[(long)r * ldc + c] = acc[i][j];
        }
    }
}

// ---------------- causal softmax in-place on scores (scale + mask inside) ----------------
__global__ __launch_bounds__(256)
void softmax_kernel(float* __restrict__ sc, const int* __restrict__ amask) {
    const int row = blockIdx.x, tid = threadIdx.x;
    float* srow = sc + ((long)blockIdx.y * T + row) * T;
    const int n = row + 1;  // valid cols
    __shared__ float red[4];
    __shared__ float share;
    float m = -INFINITY;
    for (int j = tid; j < n; j += 256) {
        float v = srow[j] * SCALE;
        if (!amask[j]) v = NEG;
        m = fmaxf(m, v);
    }
#pragma unroll
    for (int o = 32; o; o >>= 1) m = fmaxf(m, __shfl_down(m, o, 64));
    if ((tid & 63) == 0) red[tid >> 6] = m;
    __syncthreads();
    if (tid == 0) share = fmaxf(fmaxf(red[0], red[1]), fmaxf(red[2], red[3]));
    __syncthreads();
    m = share;
    float ssum = 0.f;
    for (int j = tid; j < n; j += 256) {
        float v = srow[j] * SCALE;
        if (!amask[j]) v = NEG;
        float e = expf(v - m);
        srow[j] = e;
        ssum += e;
    }
#pragma unroll
    for (int o = 32; o; o >>= 1) ssum += __shfl_down(ssum, o, 64);
    __syncthreads();   // protect red reuse
    if ((tid & 63) == 0) red[tid >> 6] = ssum;
    __syncthreads();
    if (tid == 0) share = red[0] + red[1] + red[2] + red[3];
    __syncthreads();
    float inv = 1.0f / share;
    for (int j = tid; j < n; j += 256) srow[j] *= inv;
    for (int j = n + tid; j < T; j += 256) srow[j] = 0.f;
}

// ---------------- extract the 4 probe outputs for one layer ----------------
__global__ void extract_kernel(const float* __restrict__ aw,
                               const int* __restrict__ S, const int* __restrict__ Sa1,
                               const int* __restrict__ S2,
                               float* __restrict__ out, int layer) {
    int h = threadIdx.x;
    if (h >= H) return;
    int s = *S, sa1 = *Sa1, s2 = *S2;
    const float* a = aw + (long)h * T * T;
    float dup  = a[(long)s2 * T + s];
    float ind  = a[(long)s2 * T + sa1];
    float prev = a[(long)(T - 1) * T + s2];
    out[0 * (L * H) + layer * H + h] = dup;
    out[1 * (L * H) + layer * H + h] = ind;
    out[2 * (L * H) + layer * H + h] = prev;
    out[3 * (L * H) + layer * H + h] = prev;  // name == prev
}

}  // namespace

extern "C" void kernel_launch(void* const* d_in, const int* in_sizes, int n_in,
                              void* d_out, int out_size, void* d_ws, size_t ws_size,
                              hipStream_t stream) {
    const int*   ids    = (const int*)  d_in[0];
    const int*   amask  = (const int*)  d_in[1];
    const float* wte    = (const float*)d_in[2];
    const float* wpe    = (const float*)d_in[3];
    const float* ln1_g  = (const float*)d_in[4];
    const float* ln1_b  = (const float*)d_in[5];
    const float* W_qkv  = (const float*)d_in[6];
    const float* b_qkv  = (const float*)d_in[7];
    const float* W_o    = (const float*)d_in[8];
    const float* b_o    = (const float*)d_in[9];
    const float* ln2_g  = (const float*)d_in[10];
    const float* ln2_b  = (const float*)d_in[11];
    const float* W_fc   = (const float*)d_in[12];
    const float* b_fc   = (const float*)d_in[13];
    const float* W_proj = (const float*)d_in[14];
    const float* b_proj = (const float*)d_in[15];
    const int*   Sp     = (const int*)  d_in[16];
    const int*   Sa1p   = (const int*)  d_in[17];
    const int*   S2p    = (const int*)  d_in[18];
    float* out = (float*)d_out;

    float* ws  = (float*)d_ws;
    float* h   = ws;                  // T*D
    float* xl  = h   + (long)T * D;   // T*D (also ln2 output)
    float* h2  = xl  + (long)T * D;   // T*D
    float* qkv = h2  + (long)T * D;   // T*3D
    float* ctx = qkv + (long)T * 3 * D;  // T*D
    float* sc  = ctx + (long)T * D;   // H*T*T  (aliased: FFN intermediate f)
    float* f   = sc;

    embed_kernel<<<(T * D + 255) / 256, 256, 0, stream>>>(ids, wte, wpe, h);

    for (int l = 0; l < L; l++) {
        // xl = ln1(h)
        ln_kernel<<<T, 256, 0, stream>>>(h, ln1_g + l * D, ln1_b + l * D, xl);
        // qkv = xl @ W_qkv[l] + b_qkv[l]
        gemm_nn<<<dim3(3 * D / 64, T / 64, 1), 256, 0, stream>>>(
            xl, W_qkv + (long)l * D * 3 * D, b_qkv + (long)l * 3 * D, nullptr, qkv,
            D, D, 3 * D, 3 * D, 0, 0, 0, 1);
        // scores[h] = Q_h @ K_h^T  (per head, causal block skip)
        gemm_nt_causal<<<dim3(T / 64, T / 64, H), 256, 0, stream>>>(
            qkv, qkv + D, sc, HD, 3 * D, 3 * D, T, 64, 64, (long)T * T);
        // softmax (scale + causal + mask) in place
        softmax_kernel<<<dim3(T, H), 256, 0, stream>>>(sc, amask);
        // probe outputs for this layer
        extract_kernel<<<1, 64, 0, stream>>>(sc, Sp, Sa1p, S2p, out, l);

        if (l == L - 1) break;  // last layer: h_new unused

        // ctx[:, h*64:(h+1)*64] = aw_h @ V_h
        gemm_nn<<<dim3(1, T / 64, H), 256, 0, stream>>>(
            sc, qkv + 2 * D, nullptr, nullptr, ctx,
            T, T, 3 * D, D, (long)T * T, 64, 64, 0);
        // h2 = h + ctx @ W_o[l] + b_o[l]
        gemm_nn<<<dim3(D / 64, T / 64, 1), 256, 0, stream>>>(
            ctx, W_o + (long)l * D * D, b_o + (long)l * D, h, h2,
            D, D, D, D, 0, 0, 0, 1 | 2);
        // xl = ln2(h2)
        ln_kernel<<<T, 256, 0, stream>>>(h2, ln2_g + l * D, ln2_b + l * D, xl);
        // f = gelu(xl @ W_fc[l] + b_fc[l])
        gemm_nn<<<dim3(FF / 64, T / 64, 1), 256, 0, stream>>>(
            xl, W_fc + (long)l * D * FF, b_fc + (long)l * FF, nullptr, f,
            D, D, FF, FF, 0, 0, 0, 1 | 4);
        // h = h2 + f @ W_proj[l] + b_proj[l]
        gemm_nn<<<dim3(D / 64, T / 64, 1), 256, 0, stream>>>(
            f, W_proj + (long)l * FF * D, b_proj + (long)l * D, h2, h,
            FF, FF, D, D, 0, 0, 0, 1 | 2);
    }
}